// Round 19
// baseline (634.753 us; speedup 1.0000x reference)
//
#include <hip/hip_runtime.h>
#include <hip/hip_bf16.h>

// B=256, N=10000, E=160000, H1=1024, H2=128
// Round 19: r18 instrumentation: kernels sum ~46us of the 88us -> ~40us is
// inter-node gap (~5-6us x 7 nodes). Fuse 6 nodes -> 3 while KEEPING TLP
// (r13 lesson: 1 block/CU starves memory):
//   init (bar+cnt) | front: 1024x256 (4/CU) fill||tiles -> bar -> gather ->
//   bar -> convertA | gemm12: 256x512 gemm1 -> bar -> gemm2.
// Hierarchical grid barrier (16 sub-counters, monotonic gen, self-restoring).

#define KPAD 10240
#define NSTEPS 10
#define ZSPLIT 16
#define ELLW 64
#define NP 10240
#define FBLK 1024    // front grid: 4 blocks/CU

typedef __attribute__((ext_vector_type(8))) short short8v;
typedef __attribute__((ext_vector_type(4))) float f32x4;

__device__ inline short f2bf(float f) {
    union { float f; unsigned u; } v; v.f = f;
    unsigned r = v.u + 0x7fffu + ((v.u >> 16) & 1u);
    return (short)(r >> 16);
}

__device__ inline float bf2f(short s) {
    union { unsigned u; float f; } v;
    v.u = ((unsigned)(unsigned short)s) << 16;
    return v.f;
}

__device__ inline void gll16(const short* g, short* l) {
    __builtin_amdgcn_global_load_lds(
        (const __attribute__((address_space(1))) void*)g,
        (__attribute__((address_space(3))) void*)l, 16, 0, 0);
}

// bar layout: [0]=front gen, [1]=front master, [2..17]=front subs,
//             [20]=gemm gen, [21]=gemm counter
__global__ void init_kernel(int* __restrict__ bar, float4* __restrict__ cntz) {
    int i = blockIdx.x * 256 + threadIdx.x;
    if (i < NP / 4) cntz[i] = make_float4(0.f, 0.f, 0.f, 0.f);
    if (blockIdx.x == 0 && threadIdx.x < 32) bar[threadIdx.x] = 0;
}

// hierarchical barrier for FBLK blocks: 16 subs x (FBLK/16) arrivals
__device__ inline void gridbar_front(int* bar) {
    __syncthreads();
    if (threadIdx.x == 0) {
        __threadfence();
        int gen = __hip_atomic_load(&bar[0], __ATOMIC_RELAXED, __HIP_MEMORY_SCOPE_AGENT);
        int sub = 2 + (blockIdx.x & 15);
        int old = atomicAdd(&bar[sub], 1);
        bool released = false;
        if (old == (FBLK / 16) - 1) {
            int m = atomicAdd(&bar[1], 1);
            if (m == 15) {
                for (int i = 0; i < 16; ++i) bar[2 + i] = 0;
                bar[1] = 0;
                __threadfence();
                atomicAdd(&bar[0], 1);
                released = true;
            }
        }
        if (!released) {
            while (__hip_atomic_load(&bar[0], __ATOMIC_ACQUIRE,
                                     __HIP_MEMORY_SCOPE_AGENT) == gen)
                __builtin_amdgcn_s_sleep(2);
        }
        __threadfence();
    }
    __syncthreads();
}

__device__ inline void gridbar256(int* bar) {
    __syncthreads();
    if (threadIdx.x == 0) {
        __threadfence();
        int gen = __hip_atomic_load(&bar[20], __ATOMIC_RELAXED, __HIP_MEMORY_SCOPE_AGENT);
        int old = atomicAdd(&bar[21], 1);
        if (old == 255) {
            bar[21] = 0;
            __threadfence();
            atomicAdd(&bar[20], 1);
        } else {
            while (__hip_atomic_load(&bar[20], __ATOMIC_ACQUIRE,
                                     __HIP_MEMORY_SCOPE_AGENT) == gen)
                __builtin_amdgcn_s_sleep(2);
        }
        __threadfence();
    }
    __syncthreads();
}

// P1: fill || transpose_scale || convertB ; P2: gather ; P3: convertA
__global__ void __launch_bounds__(256, 4)
front_kernel(const float* __restrict__ data, const float* __restrict__ gw,
             short* __restrict__ xwT, const float* __restrict__ W1,
             short* __restrict__ W1T, const int* __restrict__ ei,
             int* __restrict__ cnt, int* __restrict__ ell,
             const float* __restrict__ gcn_b, short* __restrict__ A0,
             short* __restrict__ A, int* __restrict__ bar,
             int N, int B, int H1, int E, int tTiles, int cTiles, int fBlks) {
    __shared__ short ldsbuf[18432];
    const int t = threadIdx.x;
    const int blk = blockIdx.x;

    // ---------- P1: fill + pack tiles (grid-stride over fBlks+tTiles+cTiles)
    {
        const int total = fBlks + tTiles + cTiles;
        for (int id = blk; id < total; id += FBLK) {
            if (id < fBlks) {
                int e = id * 256 + t;
                if (e < E) {
                    int s = ei[e], d = ei[E + e];
                    int c = atomicAdd(&cnt[d], 1);
                    if (c < ELLW) ell[(d << 6) + c] = s;
                }
            } else if (id < fBlks + tTiles) {
                short (*lds1)[264] = (short(*)[264])ldsbuf;
                int n0 = (id - fBlks) * 32;
                float wsc = gw[0];
                int br = t >> 3, lq = t & 7;
                bool full = (n0 + 32 <= N);
#pragma unroll
                for (int pass = 0; pass < 8; ++pass) {
                    int b = pass * 32 + br;
                    if (full) {
                        float4 v = *(const float4*)(data + (size_t)b * N + n0 + lq * 4);
                        lds1[lq * 4 + 0][b] = f2bf(v.x * wsc);
                        lds1[lq * 4 + 1][b] = f2bf(v.y * wsc);
                        lds1[lq * 4 + 2][b] = f2bf(v.z * wsc);
                        lds1[lq * 4 + 3][b] = f2bf(v.w * wsc);
                    } else {
#pragma unroll
                        for (int jj = 0; jj < 4; ++jj) {
                            int n = n0 + lq * 4 + jj;
                            float v = (n < N) ? data[(size_t)b * N + n] : 0.f;
                            lds1[lq * 4 + jj][b] = f2bf(v * wsc);
                        }
                    }
                }
                __syncthreads();
                int c = t & 31, nr = t >> 5;
#pragma unroll
                for (int pass = 0; pass < 4; ++pass) {
                    int nl = pass * 8 + nr;
                    int n = n0 + nl;
                    if (n < N)
                        *(short8v*)(xwT + (size_t)n * B + c * 8) =
                            *(const short8v*)&lds1[nl][c * 8];
                }
            } else {
                short (*lds2)[72] = (short(*)[72])ldsbuf;
                int cc = id - fBlks - tTiles;
                int nkx = KPAD >> 6;
                int kx = cc % nkx, hy = cc / nkx;
                int k0 = kx * 64, h0 = hy * 256;
                int w = t >> 6, l = t & 63;
#pragma unroll
                for (int pass = 0; pass < 16; ++pass) {
                    int kr = pass * 4 + w;
                    int k = k0 + kr;
                    if (k < N) {
                        float4 v = *(const float4*)(W1 + (size_t)k * H1 + h0 + l * 4);
                        lds2[l * 4 + 0][kr] = f2bf(v.x);
                        lds2[l * 4 + 1][kr] = f2bf(v.y);
                        lds2[l * 4 + 2][kr] = f2bf(v.z);
                        lds2[l * 4 + 3][kr] = f2bf(v.w);
                    } else {
                        lds2[l * 4 + 0][kr] = 0;
                        lds2[l * 4 + 1][kr] = 0;
                        lds2[l * 4 + 2][kr] = 0;
                        lds2[l * 4 + 3][kr] = 0;
                    }
                }
                __syncthreads();
                int c = t & 7, hr = t >> 3;
#pragma unroll
                for (int pass = 0; pass < 8; ++pass) {
                    int hl = pass * 32 + hr;
                    *(short8v*)(W1T + (size_t)(h0 + hl) * KPAD + k0 + c * 8) =
                        *(const short8v*)&lds2[hl][c * 8];
                }
            }
            __syncthreads();   // LDS WAR across grid-stride iterations
        }
    }
    gridbar_front(bar);

    // ---------- P2: gather (one wave per dst row, unroll-2)
    {
        const int lane = t & 63;
        const short4* x4 = (const short4*)xwT;
        const int B4 = B >> 2;
        const float gb = gcn_b[0];
        for (int row = blk * 4 + (t >> 6); row < N; row += FBLK * 4) {
            int dcnt = cnt[row];
            float di = rsqrtf((float)dcnt + 1.0f);
            float w = di * di;
            short4 v = x4[(size_t)row * B4 + lane];
            float ax = bf2f(v.x) * w, ay = bf2f(v.y) * w;
            float az = bf2f(v.z) * w, aw = bf2f(v.w) * w;
            const int* er = ell + ((size_t)row << 6);
            int m = dcnt < ELLW ? dcnt : ELLW;
            int i = 0;
            for (; i + 1 < m; i += 2) {
                int s0 = er[i], s1 = er[i + 1];
                float n0 = rsqrtf((float)cnt[s0] + 1.0f) * di;
                float n1 = rsqrtf((float)cnt[s1] + 1.0f) * di;
                short4 u0 = x4[(size_t)s0 * B4 + lane];
                short4 u1 = x4[(size_t)s1 * B4 + lane];
                ax = fmaf(bf2f(u0.x), n0, ax); ay = fmaf(bf2f(u0.y), n0, ay);
                az = fmaf(bf2f(u0.z), n0, az); aw = fmaf(bf2f(u0.w), n0, aw);
                ax = fmaf(bf2f(u1.x), n1, ax); ay = fmaf(bf2f(u1.y), n1, ay);
                az = fmaf(bf2f(u1.z), n1, az); aw = fmaf(bf2f(u1.w), n1, aw);
            }
            if (i < m) {
                int s0 = er[i];
                float n0 = rsqrtf((float)cnt[s0] + 1.0f) * di;
                short4 u0 = x4[(size_t)s0 * B4 + lane];
                ax = fmaf(bf2f(u0.x), n0, ax); ay = fmaf(bf2f(u0.y), n0, ay);
                az = fmaf(bf2f(u0.z), n0, az); aw = fmaf(bf2f(u0.w), n0, aw);
            }
            short4 s4;
            s4.x = f2bf(fmaxf(ax + gb, 0.f));
            s4.y = f2bf(fmaxf(ay + gb, 0.f));
            s4.z = f2bf(fmaxf(az + gb, 0.f));
            s4.w = f2bf(fmaxf(aw + gb, 0.f));
            ((short4*)(A0 + (size_t)row * B))[lane] = s4;
        }
    }
    gridbar_front(bar);

    // ---------- P3: convertA (A0 [N][256] -> A [256][KPAD])
    {
        short (*tl)[34] = (short(*)[34])ldsbuf;
        const int nkx = KPAD >> 5;                 // 320
        const int tiles = nkx * (B >> 5);          // 2560
        const int tx = t & 31, ty = t >> 5;        // 32 x 8
        for (int id = blk; id < tiles; id += FBLK) {
            int kx = id % nkx, my = id / nkx;
            int k0 = kx * 32, m0 = my * 32;
#pragma unroll
            for (int i = 0; i < 4; ++i) {
                int k = k0 + ty + i * 8;
                short v = (k < N) ? A0[(size_t)k * B + m0 + tx] : (short)0;
                tl[tx][ty + i * 8] = v;
            }
            __syncthreads();
#pragma unroll
            for (int i = 0; i < 4; ++i) {
                int m = m0 + ty + i * 8;
                A[(size_t)m * KPAD + k0 + tx] = tl[ty + i * 8][tx];
            }
            __syncthreads();
        }
    }
}

// gemm1 (r12-exact) -> gridbar256 -> gemm2 (512-thr variant, r13-proven)
__global__ void __launch_bounds__(512)
gemm12_kernel(const short* __restrict__ A, const short* __restrict__ Wt,
              float* __restrict__ hpart, const float* __restrict__ b1,
              const float* __restrict__ W2, const float* __restrict__ b2,
              float* __restrict__ out, int* __restrict__ bar) {
    __shared__ __align__(16) short ldsA[2][8192];
    __shared__ __align__(16) short ldsB[2][8192];
    const int t = threadIdx.x;
    const int blk = blockIdx.x;
    {
        const int n0 = (blk & 7) * 128;
        const int m0 = ((blk >> 3) & 1) * 128;
        const int kz = (blk >> 4) * (NSTEPS * 64);
        const int l = t & 63, w = t >> 6;
        const int wm = w >> 2, wn = w & 3;
        const int q = l >> 4, i16 = l & 15;

        const int sRow = t & 127, sKq = t >> 7;
        const short* gA = A + (size_t)(m0 + sRow) * KPAD + kz + sKq * 8;
        const short* gB = Wt + (size_t)(n0 + sRow) * KPAD + kz + sKq * 8;
        const int ld0 = w * 512;
        const int ld1 = 4096 + w * 512;

        f32x4 acc[4][2];
#pragma unroll
        for (int mi = 0; mi < 4; ++mi)
#pragma unroll
            for (int ni = 0; ni < 2; ++ni) acc[mi][ni] = (f32x4){0.f, 0.f, 0.f, 0.f};

        gll16(gA, &ldsA[0][ld0]); gll16(gA + 32, &ldsA[0][ld1]);
        gll16(gB, &ldsB[0][ld0]); gll16(gB + 32, &ldsB[0][ld1]);
        gA += 64; gB += 64;

        for (int ks = 0; ks < NSTEPS; ++ks) {
            const int cur = ks & 1;
            if (ks + 1 < NSTEPS) {
                gll16(gA, &ldsA[cur ^ 1][ld0]); gll16(gA + 32, &ldsA[cur ^ 1][ld1]);
                gll16(gB, &ldsB[cur ^ 1][ld0]); gll16(gB + 32, &ldsB[cur ^ 1][ld1]);
                gA += 64; gB += 64;
                asm volatile("s_waitcnt vmcnt(4)" ::: "memory");
            } else {
                asm volatile("s_waitcnt vmcnt(0)" ::: "memory");
            }
            __builtin_amdgcn_s_barrier();
            __builtin_amdgcn_sched_barrier(0);
            const short* bA = &ldsA[cur][0];
            const short* bB = &ldsB[cur][0];
#pragma unroll
            for (int kh = 0; kh < 2; ++kh) {
                const int kq = kh * 4 + q;
                short8v a[4], b[2];
#pragma unroll
                for (int mi = 0; mi < 4; ++mi)
                    a[mi] = *(const short8v*)&bA[kq * 1024 + (wm * 64 + mi * 16 + i16) * 8];
#pragma unroll
                for (int ni = 0; ni < 2; ++ni)
                    b[ni] = *(const short8v*)&bB[kq * 1024 + (wn * 32 + ni * 16 + i16) * 8];
#pragma unroll
                for (int mi = 0; mi < 4; ++mi)
#pragma unroll
                    for (int ni = 0; ni < 2; ++ni)
                        acc[mi][ni] = __builtin_amdgcn_mfma_f32_16x16x32_bf16(a[mi], b[ni], acc[mi][ni], 0, 0, 0);
            }
            __builtin_amdgcn_s_barrier();
        }

        // C/D layout (HW-verified): col = lane&15, row = (lane>>4)*4 + reg
        float* hp = hpart + (size_t)(blk >> 4) * (256 * 1024);
#pragma unroll
        for (int mi = 0; mi < 4; ++mi)
#pragma unroll
            for (int ni = 0; ni < 2; ++ni)
#pragma unroll
                for (int r = 0; r < 4; ++r) {
                    int mr = m0 + wm * 64 + mi * 16 + q * 4 + r;
                    int nc = n0 + wn * 32 + ni * 16 + i16;
                    hp[(size_t)mr * 1024 + nc] = acc[mi][ni][r];
                }
    }
    gridbar256(bar);
    {
        float* h_lds = (float*)&ldsA[0][0];                    // 1024 f32
        float (*partial)[128] = (float(*)[128])&ldsB[0][0];    // 4x128 f32
        const int b = blk;
#pragma unroll
        for (int i = 0; i < 2; ++i) {
            int col = t + i * 512;
            float s = 0.f;
            for (int z = 0; z < ZSPLIT; ++z)
                s += hpart[(size_t)z * (256 * 1024) + (size_t)b * 1024 + col];
            h_lds[col] = fmaxf(s + b1[col], 0.f);
        }
        __syncthreads();
        int j = t & 127, oct = t >> 7;          // 4 octs x 256 k
        const float* w2p = W2 + (size_t)(oct * 256) * 128 + j;
        const float* hp = h_lds + oct * 256;
        float s0 = 0.f, s1 = 0.f, s2 = 0.f, s3 = 0.f;
#pragma unroll 8
        for (int k = 0; k < 256; k += 4) {
            s0 = fmaf(hp[k],     w2p[(size_t)k * 128],       s0);
            s1 = fmaf(hp[k + 1], w2p[(size_t)(k + 1) * 128], s1);
            s2 = fmaf(hp[k + 2], w2p[(size_t)(k + 2) * 128], s2);
            s3 = fmaf(hp[k + 3], w2p[(size_t)(k + 3) * 128], s3);
        }
        partial[oct][j] = (s0 + s1) + (s2 + s3);
        __syncthreads();
        if (t < 128) {
            float v = b2[t];
#pragma unroll
            for (int o = 0; o < 4; ++o) v += partial[o][t];
            out[(size_t)b * 128 + t] = fmaxf(v, 0.f);
        }
    }
}

extern "C" void kernel_launch(void* const* d_in, const int* in_sizes, int n_in,
                              void* d_out, int out_size, void* d_ws, size_t ws_size,
                              hipStream_t stream) {
    const float* data = (const float*)d_in[0];
    const float* gw   = (const float*)d_in[1];
    const float* gb   = (const float*)d_in[2];
    const float* W1   = (const float*)d_in[3];
    const float* b1   = (const float*)d_in[4];
    const float* W2   = (const float*)d_in[5];
    const float* b2   = (const float*)d_in[6];
    const int*   ei   = (const int*)d_in[7];
    float* out = (float*)d_out;

    const int B  = 256;
    const int H1 = in_sizes[4];          // 1024
    const int H2 = in_sizes[6];          // 128
    const int N  = in_sizes[3] / H1;     // 10000
    const int E  = in_sizes[7] / 2;      // 160000
    (void)H2;

    int* iws = (int*)d_ws;
    int*   cnt  = iws;                               // NP ints
    int*   ell  = cnt + NP;                          // NP*ELLW ints
    int*   bar  = ell + (size_t)NP * ELLW;           // 32 ints
    short* S    = (short*)(bar + 32);
    short* A    = S;                                 // 256*KPAD
    short* W1T  = A + (size_t)256 * KPAD;            // 1024*KPAD
    short* xwT  = W1T + (size_t)1024 * KPAD;         // N*B
    short* A0   = xwT + (size_t)N * B;               // N*B
    float* hpart = (float*)xwT;                      // ZSPLIT*256*1024 f32 (overlays xwT/A0+)

    const int tTiles = (N + 31) / 32;                // 313
    const int cTiles = (KPAD / 64) * (H1 / 256);     // 640
    const int fBlks  = (E + 255) / 256;              // 625

    init_kernel<<<NP / 4 / 256, 256, 0, stream>>>(bar, (float4*)cnt);

    front_kernel<<<FBLK, 256, 0, stream>>>(data, gw, xwT, W1, W1T, ei, cnt, ell,
                                           gb, A0, A, bar, N, B, H1, E,
                                           tTiles, cTiles, fBlks);

    gemm12_kernel<<<256, 512, 0, stream>>>(A, W1T, hpart, b1, W2, b2, out, bar);
}

// Round 20
// 135.780 us; speedup vs baseline: 4.6749x; 4.6749x over previous
//
#include <hip/hip_runtime.h>
#include <hip/hip_bf16.h>

// B=256, N=10000, E=160000, H1=1024, H2=128
// Round 20: r12-exact structure (best measured, 88.0us) + ONE change:
// gemm1+gemm2 fused into gemm12 via 256-block gridbar (1 block/CU
// co-resident; the only barrier size with working evidence — r19's 1024-block
// hierarchical barrier livelocked at ~250us/barrier: 16 "sub-counters" on one
// cacheline + 1023 cross-XCD spinners). 6 nodes -> 5.

#define KPAD 10240
#define NSTEPS 10   // K-steps of 64: KCHUNK = 640
#define ZSPLIT 16
#define ELLW 64
#define NP 10240

typedef __attribute__((ext_vector_type(8))) short short8v;   // 8 bf16
typedef __attribute__((ext_vector_type(4))) float f32x4;

__device__ inline short f2bf(float f) {  // RNE fp32->bf16
    union { float f; unsigned u; } v; v.f = f;
    unsigned r = v.u + 0x7fffu + ((v.u >> 16) & 1u);
    return (short)(r >> 16);
}

__device__ inline float bf2f(short s) {
    union { unsigned u; float f; } v;
    v.u = ((unsigned)(unsigned short)s) << 16;
    return v.f;
}

__device__ inline void gll16(const short* g, short* l) {
    __builtin_amdgcn_global_load_lds(
        (const __attribute__((address_space(1))) void*)g,
        (__attribute__((address_space(3))) void*)l, 16, 0, 0);
}

// fused: transpose_scale | convertB | zero cnt + bar
__global__ void pack_kernel(const float* __restrict__ data, const float* __restrict__ gw,
                            short* __restrict__ xwT, const float* __restrict__ W1,
                            short* __restrict__ W1T, float4* __restrict__ cntz,
                            int* __restrict__ bar,
                            int N, int B, int H1, int tTiles, int cTiles) {
    __shared__ short tile[32][66];
    int id = blockIdx.x, t = threadIdx.x;
    if (id < tTiles) {
        int nt = (N + 31) >> 5;
        int xb = id % nt, yb = id / nt;
        int n0 = xb * 32, b0 = yb * 32;
        float w = gw[0];
        int tx = t & 31, ty = t >> 5;
#pragma unroll
        for (int i = 0; i < 4; ++i) {
            int b = b0 + ty + i * 8;
            int n = n0 + tx;
            float v = (n < N) ? data[(size_t)b * N + n] : 0.f;
            tile[ty + i * 8][tx] = f2bf(v * w);
        }
        __syncthreads();
#pragma unroll
        for (int i = 0; i < 4; ++i) {
            int n = n0 + ty + i * 8;
            if (n < N) xwT[(size_t)n * B + b0 + tx] = tile[tx][ty + i * 8];
        }
    } else if (id < tTiles + cTiles) {
        int c = id - tTiles;
        int nk = KPAD >> 6;
        int kx = c % nk, hy = c / nk;
        int k0 = kx * 64, h0 = hy * 32;
        int hl = t & 31, kr = t >> 5;
#pragma unroll
        for (int i = 0; i < 8; ++i) {
            int k = k0 + kr + i * 8;
            float v = (k < N) ? W1[(size_t)k * H1 + h0 + hl] : 0.f;
            tile[hl][kr + i * 8] = f2bf(v);
        }
        __syncthreads();
        int kl = t & 63, hr = t >> 6;
#pragma unroll
        for (int i = 0; i < 8; ++i) {
            int h = h0 + hr + i * 4;
            W1T[(size_t)h * KPAD + k0 + kl] = tile[hr + i * 4][kl];
        }
    } else {
        int zb = id - tTiles - cTiles;
        int i = zb * 256 + t;
        cntz[i] = make_float4(0.f, 0.f, 0.f, 0.f);
        if (zb == 0 && t < 8) bar[t] = 0;
    }
}

__global__ void ell_fill(const int* __restrict__ ei, int* __restrict__ cnt,
                         int* __restrict__ ell, int E) {
    int e = blockIdx.x * blockDim.x + threadIdx.x;
    if (e >= E) return;
    int s = ei[e], d = ei[E + e];
    int c = atomicAdd(&cnt[d], 1);
    if (c < ELLW) ell[(d << 6) + c] = s;   // defensive clamp; never hit
}

// one wave per dst row; A0[row][m] = bf16(relu(agg + gcn_b)); unroll-2
__global__ void gather_kernel(const int* __restrict__ cnt, const int* __restrict__ ell,
                              const float* __restrict__ gcn_b, const short* __restrict__ xwT,
                              short* __restrict__ A0, int N, int B) {
    int row = blockIdx.x * 4 + (threadIdx.x >> 6);
    if (row >= N) return;
    int lane = threadIdx.x & 63;
    const short4* x4 = (const short4*)xwT;
    const int B4 = B >> 2;
    float gb = gcn_b[0];
    int dcnt = cnt[row];
    float di = rsqrtf((float)dcnt + 1.0f);
    float w = di * di;
    short4 v = x4[(size_t)row * B4 + lane];
    float ax = bf2f(v.x) * w, ay = bf2f(v.y) * w, az = bf2f(v.z) * w, aw = bf2f(v.w) * w;
    const int* er = ell + ((size_t)row << 6);
    int m = dcnt < ELLW ? dcnt : ELLW;
    int i = 0;
    for (; i + 1 < m; i += 2) {
        int s0 = er[i], s1 = er[i + 1];
        float n0 = rsqrtf((float)cnt[s0] + 1.0f) * di;
        float n1 = rsqrtf((float)cnt[s1] + 1.0f) * di;
        short4 u0 = x4[(size_t)s0 * B4 + lane];
        short4 u1 = x4[(size_t)s1 * B4 + lane];
        ax = fmaf(bf2f(u0.x), n0, ax); ay = fmaf(bf2f(u0.y), n0, ay);
        az = fmaf(bf2f(u0.z), n0, az); aw = fmaf(bf2f(u0.w), n0, aw);
        ax = fmaf(bf2f(u1.x), n1, ax); ay = fmaf(bf2f(u1.y), n1, ay);
        az = fmaf(bf2f(u1.z), n1, az); aw = fmaf(bf2f(u1.w), n1, aw);
    }
    if (i < m) {
        int s0 = er[i];
        float n0 = rsqrtf((float)cnt[s0] + 1.0f) * di;
        short4 u0 = x4[(size_t)s0 * B4 + lane];
        ax = fmaf(bf2f(u0.x), n0, ax); ay = fmaf(bf2f(u0.y), n0, ay);
        az = fmaf(bf2f(u0.z), n0, az); aw = fmaf(bf2f(u0.w), n0, aw);
    }
    short4 s4;
    s4.x = f2bf(fmaxf(ax + gb, 0.f));
    s4.y = f2bf(fmaxf(ay + gb, 0.f));
    s4.z = f2bf(fmaxf(az + gb, 0.f));
    s4.w = f2bf(fmaxf(aw + gb, 0.f));
    ((short4*)(A0 + (size_t)row * B))[lane] = s4;
}

// A0 [N][256] bf16 -> A [256][KPAD] bf16 (transpose, zero-pad k>=N)
__global__ void convertA(const short* __restrict__ A0, short* __restrict__ A, int K, int M) {
    __shared__ short tile[32][34];
    int k0 = blockIdx.x * 32, m0 = blockIdx.y * 32;
    int tx = threadIdx.x, ty = threadIdx.y;
#pragma unroll
    for (int i = 0; i < 4; ++i) {
        int k = k0 + ty + i * 8;
        short v = (k < K) ? A0[(size_t)k * M + m0 + tx] : (short)0;
        tile[tx][ty + i * 8] = v;
    }
    __syncthreads();
#pragma unroll
    for (int i = 0; i < 4; ++i) {
        int m = m0 + ty + i * 8;
        A[(size_t)m * KPAD + k0 + tx] = tile[ty + i * 8][tx];
    }
}

// 256-block single-counter barrier (1 block/CU co-resident; r13/r19-proven size)
__device__ inline void gridbar256(int* bar) {
    __syncthreads();
    if (threadIdx.x == 0) {
        __threadfence();
        int gen = __hip_atomic_load(&bar[0], __ATOMIC_RELAXED, __HIP_MEMORY_SCOPE_AGENT);
        int old = atomicAdd(&bar[1], 1);
        if (old == 255) {
            bar[1] = 0;
            __threadfence();
            atomicAdd(&bar[0], 1);
        } else {
            while (__hip_atomic_load(&bar[0], __ATOMIC_ACQUIRE,
                                     __HIP_MEMORY_SCOPE_AGENT) == gen)
                __builtin_amdgcn_s_sleep(2);
        }
        __threadfence();
    }
    __syncthreads();
}

// gemm1 (r12-exact; 256 blocks = 8x2x16) -> gridbar -> gemm2 (512-thr)
__global__ void __launch_bounds__(512)
gemm12_kernel(const short* __restrict__ A, const short* __restrict__ Wt,
              float* __restrict__ hpart, const float* __restrict__ b1,
              const float* __restrict__ W2, const float* __restrict__ b2,
              float* __restrict__ out, int* __restrict__ bar) {
    __shared__ __align__(16) short ldsA[2][8192];
    __shared__ __align__(16) short ldsB[2][8192];
    const int t = threadIdx.x;
    const int blk = blockIdx.x;
    {
        const int n0 = (blk & 7) * 128;
        const int m0 = ((blk >> 3) & 1) * 128;
        const int kz = (blk >> 4) * (NSTEPS * 64);
        const int l = t & 63, w = t >> 6;
        const int wm = w >> 2, wn = w & 3;
        const int q = l >> 4, i16 = l & 15;

        const int sRow = t & 127, sKq = t >> 7;
        const short* gA = A + (size_t)(m0 + sRow) * KPAD + kz + sKq * 8;
        const short* gB = Wt + (size_t)(n0 + sRow) * KPAD + kz + sKq * 8;
        const int ld0 = w * 512;
        const int ld1 = 4096 + w * 512;

        f32x4 acc[4][2];
#pragma unroll
        for (int mi = 0; mi < 4; ++mi)
#pragma unroll
            for (int ni = 0; ni < 2; ++ni) acc[mi][ni] = (f32x4){0.f, 0.f, 0.f, 0.f};

        gll16(gA, &ldsA[0][ld0]); gll16(gA + 32, &ldsA[0][ld1]);
        gll16(gB, &ldsB[0][ld0]); gll16(gB + 32, &ldsB[0][ld1]);
        gA += 64; gB += 64;

        for (int ks = 0; ks < NSTEPS; ++ks) {
            const int cur = ks & 1;
            if (ks + 1 < NSTEPS) {
                gll16(gA, &ldsA[cur ^ 1][ld0]); gll16(gA + 32, &ldsA[cur ^ 1][ld1]);
                gll16(gB, &ldsB[cur ^ 1][ld0]); gll16(gB + 32, &ldsB[cur ^ 1][ld1]);
                gA += 64; gB += 64;
                asm volatile("s_waitcnt vmcnt(4)" ::: "memory");
            } else {
                asm volatile("s_waitcnt vmcnt(0)" ::: "memory");
            }
            __builtin_amdgcn_s_barrier();
            __builtin_amdgcn_sched_barrier(0);
            const short* bA = &ldsA[cur][0];
            const short* bB = &ldsB[cur][0];
#pragma unroll
            for (int kh = 0; kh < 2; ++kh) {
                const int kq = kh * 4 + q;
                short8v a[4], b[2];
#pragma unroll
                for (int mi = 0; mi < 4; ++mi)
                    a[mi] = *(const short8v*)&bA[kq * 1024 + (wm * 64 + mi * 16 + i16) * 8];
#pragma unroll
                for (int ni = 0; ni < 2; ++ni)
                    b[ni] = *(const short8v*)&bB[kq * 1024 + (wn * 32 + ni * 16 + i16) * 8];
#pragma unroll
                for (int mi = 0; mi < 4; ++mi)
#pragma unroll
                    for (int ni = 0; ni < 2; ++ni)
                        acc[mi][ni] = __builtin_amdgcn_mfma_f32_16x16x32_bf16(a[mi], b[ni], acc[mi][ni], 0, 0, 0);
            }
            __builtin_amdgcn_s_barrier();
        }

        // C/D layout (HW-verified): col = lane&15, row = (lane>>4)*4 + reg
        float* hp = hpart + (size_t)(blk >> 4) * (256 * 1024);
#pragma unroll
        for (int mi = 0; mi < 4; ++mi)
#pragma unroll
            for (int ni = 0; ni < 2; ++ni)
#pragma unroll
                for (int r = 0; r < 4; ++r) {
                    int mr = m0 + wm * 64 + mi * 16 + q * 4 + r;
                    int nc = n0 + wn * 32 + ni * 16 + i16;
                    hp[(size_t)mr * 1024 + nc] = acc[mi][ni][r];
                }
    }
    gridbar256(bar);
    {
        float* h_lds = (float*)&ldsA[0][0];                    // 1024 f32
        float (*partial)[128] = (float(*)[128])&ldsB[0][0];    // 4x128 f32
        const int b = blk;
#pragma unroll
        for (int i = 0; i < 2; ++i) {
            int col = t + i * 512;
            float s = 0.f;
            for (int z = 0; z < ZSPLIT; ++z)
                s += hpart[(size_t)z * (256 * 1024) + (size_t)b * 1024 + col];
            h_lds[col] = fmaxf(s + b1[col], 0.f);
        }
        __syncthreads();
        int j = t & 127, oct = t >> 7;          // 4 octs x 256 k
        const float* w2p = W2 + (size_t)(oct * 256) * 128 + j;
        const float* hp = h_lds + oct * 256;
        float s0 = 0.f, s1 = 0.f, s2 = 0.f, s3 = 0.f;
#pragma unroll 8
        for (int k = 0; k < 256; k += 4) {
            s0 = fmaf(hp[k],     w2p[(size_t)k * 128],       s0);
            s1 = fmaf(hp[k + 1], w2p[(size_t)(k + 1) * 128], s1);
            s2 = fmaf(hp[k + 2], w2p[(size_t)(k + 2) * 128], s2);
            s3 = fmaf(hp[k + 3], w2p[(size_t)(k + 3) * 128], s3);
        }
        partial[oct][j] = (s0 + s1) + (s2 + s3);
        __syncthreads();
        if (t < 128) {
            float v = b2[t];
#pragma unroll
            for (int o = 0; o < 4; ++o) v += partial[o][t];
            out[(size_t)b * 128 + t] = fmaxf(v, 0.f);
        }
    }
}

extern "C" void kernel_launch(void* const* d_in, const int* in_sizes, int n_in,
                              void* d_out, int out_size, void* d_ws, size_t ws_size,
                              hipStream_t stream) {
    const float* data = (const float*)d_in[0];
    const float* gw   = (const float*)d_in[1];
    const float* gb   = (const float*)d_in[2];
    const float* W1   = (const float*)d_in[3];
    const float* b1   = (const float*)d_in[4];
    const float* W2   = (const float*)d_in[5];
    const float* b2   = (const float*)d_in[6];
    const int*   ei   = (const int*)d_in[7];
    float* out = (float*)d_out;

    const int B  = 256;
    const int H1 = in_sizes[4];          // 1024
    const int H2 = in_sizes[6];          // 128
    const int N  = in_sizes[3] / H1;     // 10000
    const int E  = in_sizes[7] / 2;      // 160000
    (void)H2;

    int* iws = (int*)d_ws;
    int*   cnt  = iws;                               // NP ints
    int*   ell  = cnt + NP;                          // NP*ELLW ints
    int*   bar  = ell + (size_t)NP * ELLW;           // 8 ints
    short* S    = (short*)(bar + 8);
    short* A    = S;                                 // 256*KPAD
    short* W1T  = A + (size_t)256 * KPAD;            // 1024*KPAD
    short* xwT  = W1T + (size_t)1024 * KPAD;         // N*B
    short* A0   = xwT + (size_t)N * B;               // N*B
    float* hpart = (float*)xwT;                      // ZSPLIT*256*1024 f32 (overlays xwT/A0+)

    const int tTiles = ((N + 31) / 32) * (B / 32);       // 2504
    const int cTiles = (KPAD / 64) * (H1 / 32);          // 5120
    const int zBlks  = NP / 1024;                        // 10

    pack_kernel<<<tTiles + cTiles + zBlks, 256, 0, stream>>>(
        data, gw, xwT, W1, W1T, (float4*)cnt, bar, N, B, H1, tTiles, cTiles);

    ell_fill<<<(E + 255) / 256, 256, 0, stream>>>(ei, cnt, ell, E);

    gather_kernel<<<(N + 3) / 4, 256, 0, stream>>>(cnt, ell, gb, xwT, A0, N, B);

    convertA<<<dim3(KPAD / 32, B / 32), dim3(32, 8), 0, stream>>>(A0, A, N, B);

    gemm12_kernel<<<256, 512, 0, stream>>>(A, W1T, hpart, b1, W2, b2, out, bar);
}